// Round 8
// baseline (41.173 us; speedup 1.0000x reference)
//
#include <hip/hip_runtime.h>
#include <math.h>

// ---- DCT constants (fp32) ----
#define A0c 0.35355339059327373f
#define C1c 0.4903926402016152f
#define C2c 0.46193976625564337f
#define C3c 0.41573480615127262f
#define C5c 0.27778511650980114f
#define C6c 0.19134171618254492f
#define C7c 0.09754516100806417f

#define IMG_W 512
#define IMG_HW (512 * 512)

typedef float f8v __attribute__((ext_vector_type(8)));

// base JPEG tables (QUALITY=50 -> scaled table == base table exactly)
__device__ const float QLUM[64] = {
    16,11,10,16,24,40,51,61,  12,12,14,19,26,58,60,55,
    14,13,16,24,40,57,69,56,  14,17,22,29,51,87,80,62,
    18,22,37,56,68,109,103,77, 24,35,55,64,81,104,113,92,
    49,64,78,87,103,121,120,101, 72,92,95,98,112,100,103,99};
__device__ const float QCHR[64] = {
    17,18,24,47,99,99,99,99,  18,21,26,66,99,99,99,99,
    24,26,56,99,99,99,99,99,  47,66,99,99,99,99,99,99,
    99,99,99,99,99,99,99,99,  99,99,99,99,99,99,99,99,
    99,99,99,99,99,99,99,99,  99,99,99,99,99,99,99,99};

// In-place 8-point DCT-II (rows of D = 0.5*c(u)*cos((2x+1)u*pi/16))
__device__ __forceinline__ void fdct8(float v[8]) {
    float s0 = v[0] + v[7], s1 = v[1] + v[6], s2 = v[2] + v[5], s3 = v[3] + v[4];
    float d0 = v[0] - v[7], d1 = v[1] - v[6], d2 = v[2] - v[5], d3 = v[3] - v[4];
    float e0 = s0 + s3, e1 = s1 + s2, f0 = s0 - s3, f1 = s1 - s2;
    v[0] = A0c * (e0 + e1);
    v[4] = A0c * (e0 - e1);
    v[2] = C2c * f0 + C6c * f1;
    v[6] = C6c * f0 - C2c * f1;
    v[1] = C1c * d0 + C3c * d1 + C5c * d2 + C7c * d3;
    v[3] = C3c * d0 - C7c * d1 - C1c * d2 - C5c * d3;
    v[5] = C5c * d0 - C1c * d1 + C7c * d2 + C3c * d3;
    v[7] = C7c * d0 - C5c * d1 + C3c * d2 - C1c * d3;
}

// In-place 8-point inverse: x[n] = sum_u D[u][n] c[u]
__device__ __forceinline__ void idct8(float v[8]) {
    float g0 = v[0], g1 = v[1], g2 = v[2], g3 = v[3];
    float g4 = v[4], g5 = v[5], g6 = v[6], g7 = v[7];
    float ep = A0c * (g0 + g4), em = A0c * (g0 - g4);
    float t26a = C2c * g2 + C6c * g6;
    float t26b = C6c * g2 - C2c * g6;
    float e0 = ep + t26a, e1 = em + t26b, e2 = em - t26b, e3 = ep - t26a;
    float o0 = C1c * g1 + C3c * g3 + C5c * g5 + C7c * g7;
    float o1 = C3c * g1 - C7c * g3 - C1c * g5 - C5c * g7;
    float o2 = C5c * g1 - C1c * g3 + C7c * g5 + C3c * g7;
    float o3 = C7c * g1 - C5c * g3 + C3c * g5 - C1c * g7;
    v[0] = e0 + o0; v[7] = e0 - o0;
    v[1] = e1 + o1; v[6] = e1 - o1;
    v[2] = e2 + o2; v[5] = e2 - o2;
    v[3] = e3 + o3; v[4] = e3 - o3;
}

// soft quantize-dequantize
__device__ __forceinline__ float softq(float x, float q, float rq) {
    float d = x * rq;
    float rn = rintf(d);                   // nearest-even, matches jnp.round
    float t = d - rn;                      // in [-0.5, 0.5]
    float e = __expf(-30.0f * fabsf(t));   // tanh(15t) via exp
    float th = (1.0f - e) * __builtin_amdgcn_rcpf(1.0f + e);
    th = copysignf(th, t);
    return (d + 0.5f * th) * q;
}

// middle of the per-channel chain: V-DCT, soft-quant, V-iDCT (all in-lane)
__device__ __forceinline__ void midchain(float w[8], const float* qrow) {
    fdct8(w);
#pragma unroll
    for (int u = 0; u < 8; ++u) {
        float q = qrow[u];
        w[u] = softq(w[u], q, __builtin_amdgcn_rcpf(q));
    }
    idct8(w);
}

// Full per-tile chain (everything after the global loads). Stage-batched so
// the 3 channels' LDS round-trips software-pipeline (R7 ordering).
__device__ __forceinline__ void process_tile(const f8v Rv, const f8v Gv, const f8v Bv,
                                             float* xp0, float* xp1, float* xp2,
                                             int wi, int ri,
                                             const float* qrowL, const float* qrowC,
                                             float* obase) {
    float g0[8], g1[8], g2[8];
#pragma unroll
    for (int k = 0; k < 8; ++k) {
        float R = Rv[k], G = Gv[k], B = Bv[k];
        g0[k] = 0.299f * R + 0.587f * G + 0.114f * B - 0.5f;
        g1[k] = -0.168736f * R - 0.331264f * G + 0.5f * B;
        g2[k] = 0.5f * R - 0.418688f * G - 0.081312f * B;
    }
    fdct8(g0); fdct8(g1); fdct8(g2);

    // transpose-1 write bursts (private skew-9 regions)
#pragma unroll
    for (int v = 0; v < 8; ++v) xp0[v * 72 + wi] = g0[v];
#pragma unroll
    for (int v = 0; v < 8; ++v) xp1[v * 72 + wi] = g1[v];
#pragma unroll
    for (int v = 0; v < 8; ++v) xp2[v * 72 + wi] = g2[v];

    // transpose-1 read bursts
#pragma unroll
    for (int k = 0; k < 8; ++k) g0[k] = xp0[ri + k];
#pragma unroll
    for (int k = 0; k < 8; ++k) g1[k] = xp1[ri + k];
#pragma unroll
    for (int k = 0; k < 8; ++k) g2[k] = xp2[ri + k];

    // V-DCT + softq + V-iDCT, channels pipelined against transpose-2 traffic
    midchain(g0, qrowL);
#pragma unroll
    for (int k = 0; k < 8; ++k) xp0[ri + k] = g0[k];
    midchain(g1, qrowC);
#pragma unroll
    for (int k = 0; k < 8; ++k) xp1[ri + k] = g1[k];
#pragma unroll
    for (int v = 0; v < 8; ++v) g0[v] = xp0[v * 72 + wi];
    midchain(g2, qrowC);
#pragma unroll
    for (int k = 0; k < 8; ++k) xp2[ri + k] = g2[k];
#pragma unroll
    for (int v = 0; v < 8; ++v) g1[v] = xp1[v * 72 + wi];
#pragma unroll
    for (int v = 0; v < 8; ++v) g2[v] = xp2[v * 72 + wi];

    idct8(g0); idct8(g1); idct8(g2);

    f8v Ro, Go, Bo;
#pragma unroll
    for (int k = 0; k < 8; ++k) {
        float Y  = g0[k] + 0.5f;
        float Cb = g1[k];
        float Cr = g2[k];
        float R = Y + 1.402f * Cr;
        float G = Y - 0.344136f * Cb - 0.714136f * Cr;
        float B = Y + 1.772f * Cb;
        Ro[k] = fminf(fmaxf(R, 0.0f), 1.0f);
        Go[k] = fminf(fmaxf(G, 0.0f), 1.0f);
        Bo[k] = fminf(fmaxf(B, 0.0f), 1.0f);
    }
    *(f8v*)(obase) = Ro;
    *(f8v*)(obase + IMG_HW) = Go;
    *(f8v*)(obase + 2 * IMG_HW) = Bo;
}

// One wave = TWO 64x8 tiles (gw and gw+8192, i.e. images b and b+16), all 3
// channels, zero __syncthreads. Tile-1's 6 global loads are issued before
// tile-0's compute, so tile-1's HBM latency hides under ~2000 cyc of VALU/DS:
// breaks the R6/R7 convoy (loads only at wave birth -> bursty HBM).
__global__ __launch_bounds__(256) void jpeg_kernel(const float* __restrict__ x,
                                                   float* __restrict__ out) {
    __shared__ float xpose[4][3][576];  // [wave][channel][skew-9 scratch]
    __shared__ float qt[2][64];         // transposed q tables: qt[t][v*8+u] = Q[u][v]

    const int tid = threadIdx.x;
    const int wid = tid >> 6;
    const int lane = tid & 63;

    const int gw = blockIdx.x * 4 + wid;     // 0..8191
    const int bimg = gw >> 9;                // image 0..15 (tile1: +16)
    const int rem = gw & 511;
    const int gh = rem >> 3;                 // 8-row strip index
    const int tx = rem & 7;                  // 64-col tile index

    const int blk = lane & 7;
    const int row = lane >> 3;

    const size_t off = (size_t)bimg * 3 * IMG_HW +
                       (size_t)(gh * 8 + row) * IMG_W + tx * 64 + blk * 8;
    const size_t toff = (size_t)16 * 3 * IMG_HW;   // tile1 = image+16

    const float* base0 = x + off;
    const float* base1 = base0 + toff;

    // issue ALL 12 global loads first (6 per tile); compiler waits vmcnt(6)
    // before tile-0 use, leaving tile-1's in flight under tile-0 compute
    const f8v R0 = *(const f8v*)(base0);
    const f8v G0 = *(const f8v*)(base0 + IMG_HW);
    const f8v B0 = *(const f8v*)(base0 + 2 * IMG_HW);
    const f8v R1 = *(const f8v*)(base1);
    const f8v G1 = *(const f8v*)(base1 + IMG_HW);
    const f8v B1 = *(const f8v*)(base1 + 2 * IMG_HW);

    // q-table init after load issue (duplicate writes per wave; in-order DS
    // within a wave -> no barrier needed)
    {
        int u = lane & 7, v = lane >> 3;
        qt[0][lane] = QLUM[u * 8 + v];
        qt[1][lane] = QCHR[u * 8 + v];
    }

    float* xp0 = xpose[wid][0];
    float* xp1 = xpose[wid][1];
    float* xp2 = xpose[wid][2];
    const int wi = blk * 9 + row;
    const int ri = row * 72 + blk * 9;
    const float* qrowL = &qt[0][row * 8];
    const float* qrowC = &qt[1][row * 8];

    process_tile(R0, G0, B0, xp0, xp1, xp2, wi, ri, qrowL, qrowC, out + off);
    process_tile(R1, G1, B1, xp0, xp1, xp2, wi, ri, qrowL, qrowC, out + off + toff);
}

extern "C" void kernel_launch(void* const* d_in, const int* in_sizes, int n_in,
                              void* d_out, int out_size, void* d_ws, size_t ws_size,
                              hipStream_t stream) {
    const float* x = (const float*)d_in[0];
    float* out = (float*)d_out;
    // 8192 waves x 2 tiles = 16384 tiles (32 images x 512 tiles)
    const int n_wg = 2048;
    hipLaunchKernelGGL(jpeg_kernel, dim3(n_wg), dim3(256), 0, stream, x, out);
}

// Round 9
// 39.888 us; speedup vs baseline: 1.0322x; 1.0322x over previous
//
#include <hip/hip_runtime.h>
#include <math.h>

// ---- DCT constants (fp32) ----
#define A0c 0.35355339059327373f
#define C1c 0.4903926402016152f
#define C2c 0.46193976625564337f
#define C3c 0.41573480615127262f
#define C5c 0.27778511650980114f
#define C6c 0.19134171618254492f
#define C7c 0.09754516100806417f

#define IMG_W 512
#define IMG_HW (512 * 512)

typedef float f8v __attribute__((ext_vector_type(8)));

// TRANSPOSED base JPEG tables: QT[v*8+u] = Q[u][v]. QUALITY=50 -> scaled==base.
// Lane with freq-row v loads row v (8 floats) once per wave.
__device__ const float QLUMT[64] = {
    16,12,14,14,18,24,49,72,
    11,12,13,17,22,35,64,92,
    10,14,16,22,37,55,78,95,
    16,19,24,29,56,64,87,98,
    24,26,40,51,68,81,103,112,
    40,58,57,87,109,104,121,100,
    51,60,69,80,103,113,120,103,
    61,55,56,62,77,92,101,99};
__device__ const float QCHRT[64] = {   // QCHR is symmetric: transpose == itself
    17,18,24,47,99,99,99,99,
    18,21,26,66,99,99,99,99,
    24,26,56,99,99,99,99,99,
    47,66,99,99,99,99,99,99,
    99,99,99,99,99,99,99,99,
    99,99,99,99,99,99,99,99,
    99,99,99,99,99,99,99,99,
    99,99,99,99,99,99,99,99};

// In-place 8-point DCT-II (rows of D = 0.5*c(u)*cos((2x+1)u*pi/16))
__device__ __forceinline__ void fdct8(float v[8]) {
    float s0 = v[0] + v[7], s1 = v[1] + v[6], s2 = v[2] + v[5], s3 = v[3] + v[4];
    float d0 = v[0] - v[7], d1 = v[1] - v[6], d2 = v[2] - v[5], d3 = v[3] - v[4];
    float e0 = s0 + s3, e1 = s1 + s2, f0 = s0 - s3, f1 = s1 - s2;
    v[0] = A0c * (e0 + e1);
    v[4] = A0c * (e0 - e1);
    v[2] = C2c * f0 + C6c * f1;
    v[6] = C6c * f0 - C2c * f1;
    v[1] = C1c * d0 + C3c * d1 + C5c * d2 + C7c * d3;
    v[3] = C3c * d0 - C7c * d1 - C1c * d2 - C5c * d3;
    v[5] = C5c * d0 - C1c * d1 + C7c * d2 + C3c * d3;
    v[7] = C7c * d0 - C5c * d1 + C3c * d2 - C1c * d3;
}

// In-place 8-point inverse: x[n] = sum_u D[u][n] c[u]
__device__ __forceinline__ void idct8(float v[8]) {
    float g0 = v[0], g1 = v[1], g2 = v[2], g3 = v[3];
    float g4 = v[4], g5 = v[5], g6 = v[6], g7 = v[7];
    float ep = A0c * (g0 + g4), em = A0c * (g0 - g4);
    float t26a = C2c * g2 + C6c * g6;
    float t26b = C6c * g2 - C2c * g6;
    float e0 = ep + t26a, e1 = em + t26b, e2 = em - t26b, e3 = ep - t26a;
    float o0 = C1c * g1 + C3c * g3 + C5c * g5 + C7c * g7;
    float o1 = C3c * g1 - C7c * g3 - C1c * g5 - C5c * g7;
    float o2 = C5c * g1 - C1c * g3 + C7c * g5 + C3c * g7;
    float o3 = C7c * g1 - C5c * g3 + C3c * g5 - C1c * g7;
    v[0] = e0 + o0; v[7] = e0 - o0;
    v[1] = e1 + o1; v[6] = e1 - o1;
    v[2] = e2 + o2; v[5] = e2 - o2;
    v[3] = e3 + o3; v[4] = e3 - o3;
}

// soft quantize-dequantize (q, rq from registers)
__device__ __forceinline__ float softq(float x, float q, float rq) {
    float d = x * rq;
    float rn = rintf(d);                   // nearest-even, matches jnp.round
    float t = d - rn;                      // in [-0.5, 0.5]
    float e = __expf(-30.0f * fabsf(t));   // tanh(15t) via exp
    float th = (1.0f - e) * __builtin_amdgcn_rcpf(1.0f + e);
    th = copysignf(th, t);
    return (d + 0.5f * th) * q;
}

// V-DCT + softq + V-iDCT, all in-lane, q/rq from VGPRs
__device__ __forceinline__ void midchain(float w[8], const f8v q, const f8v rq) {
    fdct8(w);
#pragma unroll
    for (int u = 0; u < 8; ++u) w[u] = softq(w[u], q[u], rq[u]);
    idct8(w);
}

// Full per-tile chain after the global loads. Stage-batched so the 3 channels'
// LDS round-trips software-pipeline (R7 ordering), private skew-9 regions.
__device__ __forceinline__ void process_tile(const f8v Rv, const f8v Gv, const f8v Bv,
                                             float* xp0, float* xp1, float* xp2,
                                             int wi, int ri,
                                             const f8v qL, const f8v rqL,
                                             const f8v qC, const f8v rqC,
                                             float* obase) {
    float g0[8], g1[8], g2[8];
#pragma unroll
    for (int k = 0; k < 8; ++k) {
        float R = Rv[k], G = Gv[k], B = Bv[k];
        g0[k] = 0.299f * R + 0.587f * G + 0.114f * B - 0.5f;
        g1[k] = -0.168736f * R - 0.331264f * G + 0.5f * B;
        g2[k] = 0.5f * R - 0.418688f * G - 0.081312f * B;
    }
    fdct8(g0); fdct8(g1); fdct8(g2);

    // transpose-1 write bursts (private skew-9 regions)
#pragma unroll
    for (int v = 0; v < 8; ++v) xp0[v * 72 + wi] = g0[v];
#pragma unroll
    for (int v = 0; v < 8; ++v) xp1[v * 72 + wi] = g1[v];
#pragma unroll
    for (int v = 0; v < 8; ++v) xp2[v * 72 + wi] = g2[v];

    // transpose-1 read bursts (contiguous -> b128 pairs)
#pragma unroll
    for (int k = 0; k < 8; ++k) g0[k] = xp0[ri + k];
#pragma unroll
    for (int k = 0; k < 8; ++k) g1[k] = xp1[ri + k];
#pragma unroll
    for (int k = 0; k < 8; ++k) g2[k] = xp2[ri + k];

    // V-DCT + softq + V-iDCT, channels pipelined against transpose-2 traffic
    midchain(g0, qL, rqL);
#pragma unroll
    for (int k = 0; k < 8; ++k) xp0[ri + k] = g0[k];
    midchain(g1, qC, rqC);
#pragma unroll
    for (int k = 0; k < 8; ++k) xp1[ri + k] = g1[k];
#pragma unroll
    for (int v = 0; v < 8; ++v) g0[v] = xp0[v * 72 + wi];
    midchain(g2, qC, rqC);
#pragma unroll
    for (int k = 0; k < 8; ++k) xp2[ri + k] = g2[k];
#pragma unroll
    for (int v = 0; v < 8; ++v) g1[v] = xp1[v * 72 + wi];
#pragma unroll
    for (int v = 0; v < 8; ++v) g2[v] = xp2[v * 72 + wi];

    idct8(g0); idct8(g1); idct8(g2);

    f8v Ro, Go, Bo;
#pragma unroll
    for (int k = 0; k < 8; ++k) {
        float Y  = g0[k] + 0.5f;
        float Cb = g1[k];
        float Cr = g2[k];
        float R = Y + 1.402f * Cr;
        float G = Y - 0.344136f * Cb - 0.714136f * Cr;
        float B = Y + 1.772f * Cb;
        Ro[k] = fminf(fmaxf(R, 0.0f), 1.0f);
        Go[k] = fminf(fmaxf(G, 0.0f), 1.0f);
        Bo[k] = fminf(fmaxf(B, 0.0f), 1.0f);
    }
    *(f8v*)(obase) = Ro;
    *(f8v*)(obase + IMG_HW) = Go;
    *(f8v*)(obase + 2 * IMG_HW) = Bo;
}

// One wave = TWO 64x8 tiles (images b and b+16), zero __syncthreads.
// All 6 tile loads + q-table loads are issued up front and PINNED by a memory
// clobber (R8 lesson: without it the compiler sinks tile-1's loads to their
// use, defeating the prefetch). q/rq live in 32 VGPRs for the whole wave.
__global__ __launch_bounds__(256) void jpeg_kernel(const float* __restrict__ x,
                                                   float* __restrict__ out) {
    __shared__ float xpose[4][3][576];  // [wave][channel][skew-9 scratch]

    const int tid = threadIdx.x;
    const int wid = tid >> 6;
    const int lane = tid & 63;

    const int gw = blockIdx.x * 4 + wid;     // 0..8191
    const int bimg = gw >> 9;                // image 0..15 (tile1: +16)
    const int rem = gw & 511;
    const int gh = rem >> 3;                 // 8-row strip index
    const int tx = rem & 7;                  // 64-col tile index

    const int blk = lane & 7;
    const int row = lane >> 3;

    const size_t off = (size_t)bimg * 3 * IMG_HW +
                       (size_t)(gh * 8 + row) * IMG_W + tx * 64 + blk * 8;
    const size_t toff = (size_t)16 * 3 * IMG_HW;   // tile1 = image+16

    const float* base0 = x + off;
    const float* base1 = base0 + toff;

    // issue ALL global loads first
    const f8v R0 = *(const f8v*)(base0);
    const f8v G0 = *(const f8v*)(base0 + IMG_HW);
    const f8v B0 = *(const f8v*)(base0 + 2 * IMG_HW);
    const f8v R1 = *(const f8v*)(base1);
    const f8v G1 = *(const f8v*)(base1 + IMG_HW);
    const f8v B1 = *(const f8v*)(base1 + 2 * IMG_HW);
    const f8v qL = *(const f8v*)&QLUMT[row * 8];
    const f8v qC = *(const f8v*)&QCHRT[row * 8];

    // pin: no memory op (incl. these loads) may cross this point
    asm volatile("" ::: "memory");

    f8v rqL, rqC;
#pragma unroll
    for (int u = 0; u < 8; ++u) {
        rqL[u] = __builtin_amdgcn_rcpf(qL[u]);
        rqC[u] = __builtin_amdgcn_rcpf(qC[u]);
    }

    float* xp0 = xpose[wid][0];
    float* xp1 = xpose[wid][1];
    float* xp2 = xpose[wid][2];
    const int wi = blk * 9 + row;
    const int ri = row * 72 + blk * 9;

    process_tile(R0, G0, B0, xp0, xp1, xp2, wi, ri, qL, rqL, qC, rqC, out + off);
    process_tile(R1, G1, B1, xp0, xp1, xp2, wi, ri, qL, rqL, qC, rqC, out + off + toff);
}

extern "C" void kernel_launch(void* const* d_in, const int* in_sizes, int n_in,
                              void* d_out, int out_size, void* d_ws, size_t ws_size,
                              hipStream_t stream) {
    const float* x = (const float*)d_in[0];
    float* out = (float*)d_out;
    // 8192 waves x 2 tiles = 16384 tiles (32 images x 512 tiles)
    const int n_wg = 2048;
    hipLaunchKernelGGL(jpeg_kernel, dim3(n_wg), dim3(256), 0, stream, x, out);
}